// Round 10
// baseline (145.077 us; speedup 1.0000x reference)
//
#include <hip/hip_runtime.h>
#include <hip/hip_bf16.h>

// Shapes: B=4, NH=8, DIM=32, WS=8, WA=64, H=W=128, PLANE=16384.
// qkv:(4,8,96,128,128)f32  ch:(4,256,128,128)f32  lsc:(8)  btab:(225,8)
// pw:(256,256)  pb:(256)  ridx:(64,64)i32  out:(4,256,128,128)f32
//
// ws: biasG f32 [8][64][64] @0 (128 KB); wbf bf16 [256][256] @128K (128 KB)
//     chm f32 [4][32][16384] @256K (8 MB)

typedef __attribute__((ext_vector_type(8))) short short8v;
typedef __attribute__((ext_vector_type(4))) float f32x4;
typedef __attribute__((ext_vector_type(4))) unsigned int u32x4;
typedef __attribute__((ext_vector_type(2))) unsigned int u32x2;

#define PLANE 16384
#define LOG100 4.6051701859880914f

// hardware packed f32x2 -> bf16x2 (v_cvt_pk_bf16_f32), a = low half
static __device__ __forceinline__ unsigned pk2(float a, float b) {
  float2 t; t.x = a; t.y = b;
  __hip_bfloat162 r = __float22bfloat162_rn(t);
  unsigned u;
  __builtin_memcpy(&u, &r, 4);
  return u;
}
struct HiLo { unsigned hi, lo; };
// hi/lo split of a pair: hi = bf16(x), lo = bf16(x - hi)
static __device__ __forceinline__ HiLo split2(float x0, float x1) {
  HiLo o;
  o.hi = pk2(x0, x1);
  float h0 = __builtin_bit_cast(float, o.hi << 16);
  float h1 = __builtin_bit_cast(float, o.hi & 0xffff0000u);
  o.lo = pk2(x0 - h0, x1 - h1);
  return o;
}

__global__ __launch_bounds__(256) void prep_kernel(
    const float* __restrict__ ch, const float* __restrict__ btab,
    const int* __restrict__ ridx, const float* __restrict__ pw,
    float* __restrict__ chm, float* __restrict__ biasG,
    unsigned int* __restrict__ wbf)
{
  const int blk = blockIdx.x, tid = threadIdx.x;
  if (blk < 2048) {                       // chm: mean over 8 layers, float4
    int idx = blk * 256 + tid;            // [0, 512K) float4 units
    int b = idx >> 17, c = (idx >> 12) & 31, p4 = idx & 4095;
    const float4* s0 = (const float4*)ch + ((size_t)(b * 256 + c)) * (PLANE / 4) + p4;
    float4 a = {0.f, 0.f, 0.f, 0.f};
#pragma unroll
    for (int l = 0; l < 8; ++l) {
      float4 t = s0[(size_t)(l * 32) * (PLANE / 4)];
      a.x += t.x; a.y += t.y; a.z += t.z; a.w += t.w;
    }
    a.x *= 0.125f; a.y *= 0.125f; a.z *= 0.125f; a.w *= 0.125f;
    ((float4*)chm)[((size_t)(b * 32 + c)) * (PLANE / 4) + p4] = a;
  } else if (blk < 2176) {                // biasG[h][q][k]
    int i = (blk - 2048) * 256 + tid;
    int h = i >> 12, qk = i & 4095;
    biasG[i] = btab[ridx[qk] * 8 + h];
  } else {                                // w -> bf16 packed pairs
    int i = (blk - 2176) * 256 + tid;
    wbf[i] = pk2(pw[2 * i], pw[2 * i + 1]);
  }
}

// block = ONE window: 1024 blocks x 256 threads (4 waves).
// Each wave runs TWO heads (wv and wv+4) sequentially, then 1/4 of proj.
// LDS 32 KB: x_lds bf16 [64 pos][256 c], XOR-swizzled. ONE barrier total.
__global__ __launch_bounds__(256, 4) void fused_kernel(
    const float* __restrict__ qkv, const float* __restrict__ chm,
    const float* __restrict__ lsc, const float* __restrict__ biasG,
    const unsigned short* __restrict__ wbf, const float* __restrict__ pb,
    float* __restrict__ out)
{
  __shared__ __align__(16) char smem[32768];   // x_lds [64][512B]

  const int tid = threadIdx.x;
  const int orig = blockIdx.x;
  const int win = ((orig & 7) << 7) | (orig >> 3);  // XCD swizzle, pair-preserving
  const int b  = win >> 8;
  const int wy = (win >> 4) & 15;
  const int wx = win & 15;
  const int y0 = wy << 3, x0 = wx << 3;

  const int wv = tid >> 6, lane = tid & 63;
  const int lg = lane >> 4, lr = lane & 15;

  const float* cg = chm + (size_t)(b * 32) * PLANE;

#pragma unroll 1
  for (int hh = 0; hh < 2; ++hh) {
    const int h = wv + 4 * hh;
    const size_t qbase = ((size_t)((b * 8 + h) * 96)) * PLANE;
    const float* qg = qkv + qbase;
    const float* kg = qg + (size_t)32 * PLANE;
    const float* vg = qg + (size_t)64 * PLANE;
    const float scale = __expf(fminf(lsc[h], LOG100));

    // ---- V*chm frags, sigma-permuted: elem j <- kpos 4lg+(j&3)+16(j>>2)+32m
    short8v vf[2][2];
#pragma unroll
    for (int dt = 0; dt < 2; ++dt) {
      const int d = 16 * dt + lr;
      const float* vp = vg + (size_t)d * PLANE;
      const float* cp = cg + (size_t)d * PLANE;
#pragma unroll
      for (int m = 0; m < 2; ++m) {
        int ka = 4 * lg + 32 * m, kb = ka + 16;
        int spa = (y0 + (ka >> 3)) * 128 + x0 + (ka & 7);
        int spb = (y0 + (kb >> 3)) * 128 + x0 + (kb & 7);
        float4 va = *(const float4*)(vp + spa);
        float4 ca = *(const float4*)(cp + spa);
        float4 vb = *(const float4*)(vp + spb);
        float4 cb = *(const float4*)(cp + spb);
        u32x4 u;
        u[0] = pk2(va.x * ca.x, va.y * ca.y);
        u[1] = pk2(va.z * ca.z, va.w * ca.w);
        u[2] = pk2(vb.x * cb.x, vb.y * cb.y);
        u[3] = pk2(vb.z * cb.z, vb.w * cb.w);
        vf[dt][m] = __builtin_bit_cast(short8v, u);
      }
    }

    // ---- K raw loads, per-position l2-norm, normalize, hi/lo split
    short8v khi[4], klo[4];
#pragma unroll
    for (int kt = 0; kt < 4; ++kt) {
      int kpos = 16 * kt + lr;
      int spk = (y0 + (kpos >> 3)) * 128 + x0 + (kpos & 7);
      float kk[8];
#pragma unroll
      for (int j = 0; j < 8; ++j)
        kk[j] = kg[(size_t)(8 * lg + j) * PLANE + spk];
      float nr = 0.f;
#pragma unroll
      for (int j = 0; j < 8; ++j) nr = fmaf(kk[j], kk[j], nr);
      nr += __shfl_xor(nr, 16);
      nr += __shfl_xor(nr, 32);
      float iv = 1.f / fmaxf(sqrtf(nr), 1e-12f);
      u32x4 uh, ul;
#pragma unroll
      for (int p2 = 0; p2 < 4; ++p2) {
        HiLo hl = split2(kk[2 * p2] * iv, kk[2 * p2 + 1] * iv);
        uh[p2] = hl.hi;
        ul[p2] = hl.lo;
      }
      khi[kt] = __builtin_bit_cast(short8v, uh);
      klo[kt] = __builtin_bit_cast(short8v, ul);
    }

    const float* bgh = biasG + (h << 12);

    // ---- 4 q-strips, Q loads pipelined one strip ahead (static dbuf)
    float qa[8], qb[8];
    {
      int spq = (y0 + (lr >> 3)) * 128 + x0 + (lr & 7);   // strip 0
#pragma unroll
      for (int j = 0; j < 8; ++j)
        qa[j] = qg[(size_t)(8 * lg + j) * PLANE + spq];
    }
#pragma unroll 1
    for (int st = 0; st < 4; ++st) {
      if (st < 3) {
        int qn = 16 * (st + 1) + lr;
        int spq = (y0 + (qn >> 3)) * 128 + x0 + (qn & 7);
#pragma unroll
        for (int j = 0; j < 8; ++j)
          qb[j] = qg[(size_t)(8 * lg + j) * PLANE + spq];
      }
      const int q = 16 * st + lr;

      float nrq = 0.f;
#pragma unroll
      for (int j = 0; j < 8; ++j) nrq = fmaf(qa[j], qa[j], nrq);
      nrq += __shfl_xor(nrq, 16);
      nrq += __shfl_xor(nrq, 32);
      const float fq = scale / fmaxf(sqrtf(nrq), 1e-12f);

      short8v qhi, qlo;
      {
        u32x4 uh, ul;
#pragma unroll
        for (int p2 = 0; p2 < 4; ++p2) {
          HiLo hl = split2(qa[2 * p2] * fq, qa[2 * p2 + 1] * fq);
          uh[p2] = hl.hi;
          ul[p2] = hl.lo;
        }
        qhi = __builtin_bit_cast(short8v, uh);
        qlo = __builtin_bit_cast(short8v, ul);
      }

      // S^T tiles + logits + lane-local softmax (kpos = 16kt + 4lg + r)
      const float4* bq = (const float4*)(bgh + (q << 6));
      float e[16], mx = -1e30f;
      __builtin_amdgcn_s_setprio(1);
#pragma unroll
      for (int kt = 0; kt < 4; ++kt) {
        f32x4 a = {0.f, 0.f, 0.f, 0.f};
        a = __builtin_amdgcn_mfma_f32_16x16x32_bf16(klo[kt], qhi, a, 0, 0, 0);
        a = __builtin_amdgcn_mfma_f32_16x16x32_bf16(khi[kt], qlo, a, 0, 0, 0);
        a = __builtin_amdgcn_mfma_f32_16x16x32_bf16(khi[kt], qhi, a, 0, 0, 0);
        float4 b4 = bq[4 * kt + lg];
        float bb[4] = {b4.x, b4.y, b4.z, b4.w};
#pragma unroll
        for (int r = 0; r < 4; ++r) {
          float lv = a[r] + bb[r];
          e[4 * kt + r] = lv;
          mx = fmaxf(mx, lv);
        }
      }
      __builtin_amdgcn_s_setprio(0);
      mx = fmaxf(mx, __shfl_xor(mx, 16));
      mx = fmaxf(mx, __shfl_xor(mx, 32));
      float s = 0.f;
#pragma unroll
      for (int i = 0; i < 16; ++i) { e[i] = __expf(e[i] - mx); s += e[i]; }
      s += __shfl_xor(s, 16);
      s += __shfl_xor(s, 32);
      float rl = 1.f / s;

      // P B-frags: pf[m][j] = bf16(e[8m + j])
      short8v pf[2];
#pragma unroll
      for (int m = 0; m < 2; ++m) {
        u32x4 up;
#pragma unroll
        for (int p2 = 0; p2 < 4; ++p2)
          up[p2] = pk2(e[8 * m + 2 * p2], e[8 * m + 2 * p2 + 1]);
        pf[m] = __builtin_bit_cast(short8v, up);
      }

      // PV; store to swizzled x_lds: byte = pl*512 + (2c ^ ((pl&7)<<4))
      const int pl = q;
      __builtin_amdgcn_s_setprio(1);
#pragma unroll
      for (int dt = 0; dt < 2; ++dt) {
        f32x4 o = {0.f, 0.f, 0.f, 0.f};
        o = __builtin_amdgcn_mfma_f32_16x16x32_bf16(vf[dt][0], pf[0], o, 0, 0, 0);
        o = __builtin_amdgcn_mfma_f32_16x16x32_bf16(vf[dt][1], pf[1], o, 0, 0, 0);
        u32x2 ww;
        ww[0] = pk2(o[0] * rl, o[1] * rl);
        ww[1] = pk2(o[2] * rl, o[3] * rl);
        unsigned off = (unsigned)(pl * 512)
                     + (((unsigned)(64 * h + 32 * dt + 8 * lg)) ^ ((unsigned)(pl & 7) << 4));
        *(u32x2*)(smem + off) = ww;
      }
      __builtin_amdgcn_s_setprio(0);

      // rotate Q double-buffer
#pragma unroll
      for (int j = 0; j < 8; ++j) qa[j] = qb[j];
    }
  }
  __syncthreads();   // the only barrier

  // ---- projection: wave wv -> o in [64wv, 64wv+64) x 64 positions
  f32x4 acc[4][4];
#pragma unroll
  for (int i = 0; i < 4; ++i)
#pragma unroll
    for (int j = 0; j < 4; ++j) acc[i][j] = (f32x4){0.f, 0.f, 0.f, 0.f};

#pragma unroll 1
  for (int kc = 0; kc < 8; ++kc) {
    short8v wf[4];
#pragma unroll
    for (int ot = 0; ot < 4; ++ot)
      wf[ot] = *(const short8v*)(wbf + (size_t)(64 * wv + 16 * ot + lr) * 256 + 32 * kc + 8 * lg);
    short8v xf[4];
#pragma unroll
    for (int pt = 0; pt < 4; ++pt) {
      int pl = 16 * pt + lr;
      unsigned off = (unsigned)(pl * 512)
                   + (((unsigned)(64 * kc + 16 * lg)) ^ ((unsigned)(pl & 7) << 4));
      xf[pt] = *(const short8v*)(smem + off);
    }
    __builtin_amdgcn_s_setprio(1);
#pragma unroll
    for (int ot = 0; ot < 4; ++ot)
#pragma unroll
      for (int pt = 0; pt < 4; ++pt)
        acc[ot][pt] = __builtin_amdgcn_mfma_f32_16x16x32_bf16(wf[ot], xf[pt], acc[ot][pt], 0, 0, 0);
    __builtin_amdgcn_s_setprio(0);
  }

#pragma unroll
  for (int ot = 0; ot < 4; ++ot) {
#pragma unroll
    for (int r = 0; r < 4; ++r) {
      int o = 64 * wv + 16 * ot + 4 * lg + r;
      float bv = pb[o];
      float* op = out + ((size_t)(b * 256 + o)) * PLANE;
#pragma unroll
      for (int pt = 0; pt < 4; ++pt) {
        int p = 16 * pt + lr;
        op[(y0 + (p >> 3)) * 128 + x0 + (p & 7)] = acc[ot][pt][r] + bv;
      }
    }
  }
}

extern "C" void kernel_launch(void* const* d_in, const int* in_sizes, int n_in,
                              void* d_out, int out_size, void* d_ws, size_t ws_size,
                              hipStream_t stream) {
  const float* qkv  = (const float*)d_in[0];
  const float* ch   = (const float*)d_in[1];
  const float* lsc  = (const float*)d_in[2];
  const float* btab = (const float*)d_in[3];
  const float* pw   = (const float*)d_in[4];
  const float* pb   = (const float*)d_in[5];
  const int*   ridx = (const int*)d_in[6];
  float* out = (float*)d_out;

  char* ws = (char*)d_ws;
  float*          biasG = (float*)ws;                      // 128 KB
  unsigned short* wbf   = (unsigned short*)(ws + 131072);  // 128 KB
  float*          chm   = (float*)(ws + 262144);           // 8 MB

  prep_kernel<<<dim3(2304), dim3(256), 0, stream>>>(ch, btab, ridx, pw,
                                                    chm, biasG, (unsigned int*)wbf);
  fused_kernel<<<dim3(1024), dim3(256), 0, stream>>>(qkv, chm, lsc, biasG,
                                                     wbf, pb, out);
}

// Round 11
// 117.204 us; speedup vs baseline: 1.2378x; 1.2378x over previous
//
#include <hip/hip_runtime.h>
#include <hip/hip_bf16.h>

// Shapes: B=4, NH=8, DIM=32, WS=8, WA=64, H=W=128, PLANE=16384.
// qkv:(4,8,96,128,128)f32  ch:(4,256,128,128)f32  lsc:(8)  btab:(225,8)
// pw:(256,256)  pb:(256)  ridx:(64,64)i32  out:(4,256,128,128)f32
//
// ws: biasG f32 [8][64][64] @0 (128 KB); wbf bf16 [256][256] @128K (128 KB)
//     chm f32 [4][32][16384] @256K (8 MB)

typedef __attribute__((ext_vector_type(8))) short short8v;
typedef __attribute__((ext_vector_type(4))) float f32x4;
typedef __attribute__((ext_vector_type(4))) unsigned int u32x4;
typedef __attribute__((ext_vector_type(2))) unsigned int u32x2;

#define PLANE 16384
#define LOG100 4.6051701859880914f

// hardware packed f32x2 -> bf16x2 (v_cvt_pk_bf16_f32), a = low half
static __device__ __forceinline__ unsigned pk2(float a, float b) {
  float2 t; t.x = a; t.y = b;
  __hip_bfloat162 r = __float22bfloat162_rn(t);
  unsigned u;
  __builtin_memcpy(&u, &r, 4);
  return u;
}
struct HiLo { unsigned hi, lo; };
// hi/lo split of a pair: hi = bf16(x), lo = bf16(x - hi)
static __device__ __forceinline__ HiLo split2(float x0, float x1) {
  HiLo o;
  o.hi = pk2(x0, x1);
  float h0 = __builtin_bit_cast(float, o.hi << 16);
  float h1 = __builtin_bit_cast(float, o.hi & 0xffff0000u);
  o.lo = pk2(x0 - h0, x1 - h1);
  return o;
}

__global__ __launch_bounds__(256) void prep_kernel(
    const float* __restrict__ ch, const float* __restrict__ btab,
    const int* __restrict__ ridx, const float* __restrict__ pw,
    float* __restrict__ chm, float* __restrict__ biasG,
    unsigned int* __restrict__ wbf)
{
  const int blk = blockIdx.x, tid = threadIdx.x;
  if (blk < 2048) {                       // chm: mean over 8 layers, float4
    int idx = blk * 256 + tid;            // [0, 512K) float4 units
    int b = idx >> 17, c = (idx >> 12) & 31, p4 = idx & 4095;
    const float4* s0 = (const float4*)ch + ((size_t)(b * 256 + c)) * (PLANE / 4) + p4;
    float4 a = {0.f, 0.f, 0.f, 0.f};
#pragma unroll
    for (int l = 0; l < 8; ++l) {
      float4 t = s0[(size_t)(l * 32) * (PLANE / 4)];
      a.x += t.x; a.y += t.y; a.z += t.z; a.w += t.w;
    }
    a.x *= 0.125f; a.y *= 0.125f; a.z *= 0.125f; a.w *= 0.125f;
    ((float4*)chm)[((size_t)(b * 32 + c)) * (PLANE / 4) + p4] = a;
  } else if (blk < 2176) {                // biasG[h][q][k]
    int i = (blk - 2048) * 256 + tid;
    int h = i >> 12, qk = i & 4095;
    biasG[i] = btab[ridx[qk] * 8 + h];
  } else {                                // w -> bf16 packed pairs
    int i = (blk - 2176) * 256 + tid;
    wbf[i] = pk2(pw[2 * i], pw[2 * i + 1]);
  }
}

// block = ONE window: 1024 blocks x 256 threads (4 waves).
// Each wave runs TWO heads (wv and wv+4) sequentially, then 1/4 of proj.
// LDS 32 KB: x_lds bf16 [64 pos][256 c], XOR-swizzled. ONE barrier total.
// launch_bounds WITHOUT a min-waves floor: let the allocator take ~110 VGPR
// (4 waves/SIMD, 4 blocks/CU = one co-resident generation) with NO spill.
__global__ __launch_bounds__(256) void fused_kernel(
    const float* __restrict__ qkv, const float* __restrict__ chm,
    const float* __restrict__ lsc, const float* __restrict__ biasG,
    const unsigned short* __restrict__ wbf, const float* __restrict__ pb,
    float* __restrict__ out)
{
  __shared__ __align__(16) char smem[32768];   // x_lds [64][512B]

  const int tid = threadIdx.x;
  const int orig = blockIdx.x;
  const int win = ((orig & 7) << 7) | (orig >> 3);  // XCD swizzle, pair-preserving
  const int b  = win >> 8;
  const int wy = (win >> 4) & 15;
  const int wx = win & 15;
  const int y0 = wy << 3, x0 = wx << 3;

  const int wv = tid >> 6, lane = tid & 63;
  const int lg = lane >> 4, lr = lane & 15;

  const float* cg = chm + (size_t)(b * 32) * PLANE;

#pragma unroll 1
  for (int hh = 0; hh < 2; ++hh) {
    const int h = wv + 4 * hh;
    const size_t qbase = ((size_t)((b * 8 + h) * 96)) * PLANE;
    const float* qg = qkv + qbase;
    const float* kg = qg + (size_t)32 * PLANE;
    const float* vg = qg + (size_t)64 * PLANE;
    const float scale = __expf(fminf(lsc[h], LOG100));

    // ---- V*chm frags, sigma-permuted: elem j <- kpos 4lg+(j&3)+16(j>>2)+32m
    short8v vf[2][2];
#pragma unroll
    for (int dt = 0; dt < 2; ++dt) {
      const int d = 16 * dt + lr;
      const float* vp = vg + (size_t)d * PLANE;
      const float* cp = cg + (size_t)d * PLANE;
#pragma unroll
      for (int m = 0; m < 2; ++m) {
        int ka = 4 * lg + 32 * m, kb = ka + 16;
        int spa = (y0 + (ka >> 3)) * 128 + x0 + (ka & 7);
        int spb = (y0 + (kb >> 3)) * 128 + x0 + (kb & 7);
        float4 va = *(const float4*)(vp + spa);
        float4 ca = *(const float4*)(cp + spa);
        float4 vb = *(const float4*)(vp + spb);
        float4 cb = *(const float4*)(cp + spb);
        u32x4 u;
        u[0] = pk2(va.x * ca.x, va.y * ca.y);
        u[1] = pk2(va.z * ca.z, va.w * ca.w);
        u[2] = pk2(vb.x * cb.x, vb.y * cb.y);
        u[3] = pk2(vb.z * cb.z, vb.w * cb.w);
        vf[dt][m] = __builtin_bit_cast(short8v, u);
      }
    }

    // ---- K raw loads, per-position l2-norm, normalize, hi/lo split
    short8v khi[4], klo[4];
#pragma unroll
    for (int kt = 0; kt < 4; ++kt) {
      int kpos = 16 * kt + lr;
      int spk = (y0 + (kpos >> 3)) * 128 + x0 + (kpos & 7);
      float kk[8];
#pragma unroll
      for (int j = 0; j < 8; ++j)
        kk[j] = kg[(size_t)(8 * lg + j) * PLANE + spk];
      float nr = 0.f;
#pragma unroll
      for (int j = 0; j < 8; ++j) nr = fmaf(kk[j], kk[j], nr);
      nr += __shfl_xor(nr, 16);
      nr += __shfl_xor(nr, 32);
      float iv = 1.f / fmaxf(sqrtf(nr), 1e-12f);
      u32x4 uh, ul;
#pragma unroll
      for (int p2 = 0; p2 < 4; ++p2) {
        HiLo hl = split2(kk[2 * p2] * iv, kk[2 * p2 + 1] * iv);
        uh[p2] = hl.hi;
        ul[p2] = hl.lo;
      }
      khi[kt] = __builtin_bit_cast(short8v, uh);
      klo[kt] = __builtin_bit_cast(short8v, ul);
    }

    const float* bgh = biasG + (h << 12);

    // ---- 4 q-strips, Q loads pipelined one strip ahead (static dbuf)
    float qa[8], qb[8];
    {
      int spq = (y0 + (lr >> 3)) * 128 + x0 + (lr & 7);   // strip 0
#pragma unroll
      for (int j = 0; j < 8; ++j)
        qa[j] = qg[(size_t)(8 * lg + j) * PLANE + spq];
    }
#pragma unroll 1
    for (int st = 0; st < 4; ++st) {
      if (st < 3) {
        int qn = 16 * (st + 1) + lr;
        int spq = (y0 + (qn >> 3)) * 128 + x0 + (qn & 7);
#pragma unroll
        for (int j = 0; j < 8; ++j)
          qb[j] = qg[(size_t)(8 * lg + j) * PLANE + spq];
      }
      const int q = 16 * st + lr;

      float nrq = 0.f;
#pragma unroll
      for (int j = 0; j < 8; ++j) nrq = fmaf(qa[j], qa[j], nrq);
      nrq += __shfl_xor(nrq, 16);
      nrq += __shfl_xor(nrq, 32);
      const float fq = scale / fmaxf(sqrtf(nrq), 1e-12f);

      short8v qhi, qlo;
      {
        u32x4 uh, ul;
#pragma unroll
        for (int p2 = 0; p2 < 4; ++p2) {
          HiLo hl = split2(qa[2 * p2] * fq, qa[2 * p2 + 1] * fq);
          uh[p2] = hl.hi;
          ul[p2] = hl.lo;
        }
        qhi = __builtin_bit_cast(short8v, uh);
        qlo = __builtin_bit_cast(short8v, ul);
      }

      // S^T tiles + logits + lane-local softmax (kpos = 16kt + 4lg + r)
      const float4* bq = (const float4*)(bgh + (q << 6));
      float e[16], mx = -1e30f;
      __builtin_amdgcn_s_setprio(1);
#pragma unroll
      for (int kt = 0; kt < 4; ++kt) {
        f32x4 a = {0.f, 0.f, 0.f, 0.f};
        a = __builtin_amdgcn_mfma_f32_16x16x32_bf16(klo[kt], qhi, a, 0, 0, 0);
        a = __builtin_amdgcn_mfma_f32_16x16x32_bf16(khi[kt], qlo, a, 0, 0, 0);
        a = __builtin_amdgcn_mfma_f32_16x16x32_bf16(khi[kt], qhi, a, 0, 0, 0);
        float4 b4 = bq[4 * kt + lg];
        float bb[4] = {b4.x, b4.y, b4.z, b4.w};
#pragma unroll
        for (int r = 0; r < 4; ++r) {
          float lv = a[r] + bb[r];
          e[4 * kt + r] = lv;
          mx = fmaxf(mx, lv);
        }
      }
      __builtin_amdgcn_s_setprio(0);
      mx = fmaxf(mx, __shfl_xor(mx, 16));
      mx = fmaxf(mx, __shfl_xor(mx, 32));
      float s = 0.f;
#pragma unroll
      for (int i = 0; i < 16; ++i) { e[i] = __expf(e[i] - mx); s += e[i]; }
      s += __shfl_xor(s, 16);
      s += __shfl_xor(s, 32);
      float rl = 1.f / s;

      // P B-frags: pf[m][j] = bf16(e[8m + j])
      short8v pf[2];
#pragma unroll
      for (int m = 0; m < 2; ++m) {
        u32x4 up;
#pragma unroll
        for (int p2 = 0; p2 < 4; ++p2)
          up[p2] = pk2(e[8 * m + 2 * p2], e[8 * m + 2 * p2 + 1]);
        pf[m] = __builtin_bit_cast(short8v, up);
      }

      // PV; store to swizzled x_lds: byte = pl*512 + (2c ^ ((pl&7)<<4))
      const int pl = q;
      __builtin_amdgcn_s_setprio(1);
#pragma unroll
      for (int dt = 0; dt < 2; ++dt) {
        f32x4 o = {0.f, 0.f, 0.f, 0.f};
        o = __builtin_amdgcn_mfma_f32_16x16x32_bf16(vf[dt][0], pf[0], o, 0, 0, 0);
        o = __builtin_amdgcn_mfma_f32_16x16x32_bf16(vf[dt][1], pf[1], o, 0, 0, 0);
        u32x2 ww;
        ww[0] = pk2(o[0] * rl, o[1] * rl);
        ww[1] = pk2(o[2] * rl, o[3] * rl);
        unsigned off = (unsigned)(pl * 512)
                     + (((unsigned)(64 * h + 32 * dt + 8 * lg)) ^ ((unsigned)(pl & 7) << 4));
        *(u32x2*)(smem + off) = ww;
      }
      __builtin_amdgcn_s_setprio(0);

      // rotate Q double-buffer
#pragma unroll
      for (int j = 0; j < 8; ++j) qa[j] = qb[j];
    }
  }
  __syncthreads();   // the only barrier

  // ---- projection: wave wv -> o in [64wv, 64wv+64) x 64 positions
  f32x4 acc[4][4];
#pragma unroll
  for (int i = 0; i < 4; ++i)
#pragma unroll
    for (int j = 0; j < 4; ++j) acc[i][j] = (f32x4){0.f, 0.f, 0.f, 0.f};

#pragma unroll 1
  for (int kc = 0; kc < 8; ++kc) {
    short8v wf[4];
#pragma unroll
    for (int ot = 0; ot < 4; ++ot)
      wf[ot] = *(const short8v*)(wbf + (size_t)(64 * wv + 16 * ot + lr) * 256 + 32 * kc + 8 * lg);
    short8v xf[4];
#pragma unroll
    for (int pt = 0; pt < 4; ++pt) {
      int pl = 16 * pt + lr;
      unsigned off = (unsigned)(pl * 512)
                   + (((unsigned)(64 * kc + 16 * lg)) ^ ((unsigned)(pl & 7) << 4));
      xf[pt] = *(const short8v*)(smem + off);
    }
    __builtin_amdgcn_s_setprio(1);
#pragma unroll
    for (int ot = 0; ot < 4; ++ot)
#pragma unroll
      for (int pt = 0; pt < 4; ++pt)
        acc[ot][pt] = __builtin_amdgcn_mfma_f32_16x16x32_bf16(wf[ot], xf[pt], acc[ot][pt], 0, 0, 0);
    __builtin_amdgcn_s_setprio(0);
  }

#pragma unroll
  for (int ot = 0; ot < 4; ++ot) {
#pragma unroll
    for (int r = 0; r < 4; ++r) {
      int o = 64 * wv + 16 * ot + 4 * lg + r;
      float bv = pb[o];
      float* op = out + ((size_t)(b * 256 + o)) * PLANE;
#pragma unroll
      for (int pt = 0; pt < 4; ++pt) {
        int p = 16 * pt + lr;
        op[(y0 + (p >> 3)) * 128 + x0 + (p & 7)] = acc[ot][pt][r] + bv;
      }
    }
  }
}

extern "C" void kernel_launch(void* const* d_in, const int* in_sizes, int n_in,
                              void* d_out, int out_size, void* d_ws, size_t ws_size,
                              hipStream_t stream) {
  const float* qkv  = (const float*)d_in[0];
  const float* ch   = (const float*)d_in[1];
  const float* lsc  = (const float*)d_in[2];
  const float* btab = (const float*)d_in[3];
  const float* pw   = (const float*)d_in[4];
  const float* pb   = (const float*)d_in[5];
  const int*   ridx = (const int*)d_in[6];
  float* out = (float*)d_out;

  char* ws = (char*)d_ws;
  float*          biasG = (float*)ws;                      // 128 KB
  unsigned short* wbf   = (unsigned short*)(ws + 131072);  // 128 KB
  float*          chm   = (float*)(ws + 262144);           // 8 MB

  prep_kernel<<<dim3(2304), dim3(256), 0, stream>>>(ch, btab, ridx, pw,
                                                    chm, biasG, (unsigned int*)wbf);
  fused_kernel<<<dim3(1024), dim3(256), 0, stream>>>(qkv, chm, lsc, biasG,
                                                     wbf, pb, out);
}